// Round 5
// baseline (940.445 us; speedup 1.0000x reference)
//
#include <hip/hip_runtime.h>
#include <hip/hip_bf16.h>

#define NB 262144
#define RTILE 64

typedef __bf16 bf16x8 __attribute__((ext_vector_type(8)));
typedef float f32x4 __attribute__((ext_vector_type(4)));

// ---- packed bf16 weight buffer ----
// MFMA layers fragment-ordered: fragment (colTile,ks) at
//   off + ((colTile*KSTRIDE + ks)*64 + lane)*8
// lane's elems: W[col=colTile*16+(lane&15)][k=ks*32+(lane>>4)*8+e].
// Wsig/Wrgb plain row-major.
#define OFF_W0   0        // [256][64]   (K 63->64)
#define OFF_W1   16384    // [256][256]
#define OFF_W2   81920
#define OFF_W3   147456
#define OFF_W4   212992
#define OFF_W5   278528   // [256][320]  (K 319->320)
#define OFF_W6   360448
#define OFF_W7   425984
#define OFF_WSIG 491520   // [1][256] plain
#define OFF_W8   491776   // [256][256]
#define OFF_W9   557312   // [128][288]  (K 283->288)
#define OFF_W10  594176   // [128][128]
#define OFF_W11  610560
#define OFF_W12  626944
#define OFF_WRGB 643328   // [3][128] plain
#define WTOTAL   643712

__device__ __align__(16) unsigned short g_w[WTOTAL];

__device__ __forceinline__ unsigned short f2bfu(float f) {
  __bf16 h = (__bf16)f;
  return __builtin_bit_cast(unsigned short, h);
}

__global__ void prep_kernel(const float* W0, const float* W1, const float* W2,
                            const float* W3, const float* W4, const float* W5,
                            const float* W6, const float* W7, const float* Wsig,
                            const float* W8, const float* W9, const float* W10,
                            const float* W11, const float* W12, const float* Wrgb) {
  const float* srcs[15] = {W0,W1,W2,W3,W4,W5,W6,W7,Wsig,W8,W9,W10,W11,W12,Wrgb};
  const int dsto[16] = {OFF_W0,OFF_W1,OFF_W2,OFF_W3,OFF_W4,OFF_W5,OFF_W6,OFF_W7,
                        OFF_WSIG,OFF_W8,OFF_W9,OFF_W10,OFF_W11,OFF_W12,OFF_WRGB,WTOTAL};
  const int kpad[15] = {64,256,256,256,256,320,256,256,256,256,288,128,128,128,128};
  const int ksrc[15] = {63,256,256,256,256,319,256,256,256,256,283,128,128,128,128};
  int idx = blockIdx.x * blockDim.x + threadIdx.x;
  if (idx >= WTOTAL) return;
  int r = 0;
  for (int i = 1; i < 15; ++i) if (idx >= dsto[i]) r = i;
  int local = idx - dsto[r];
  float v;
  if (r == 8 || r == 14) {             // head weights: plain row-major
    int o = local / kpad[r];
    int k = local - o * kpad[r];
    v = (k < ksrc[r]) ? srcs[r][o * ksrc[r] + k] : 0.0f;
  } else {                             // MFMA layers: fragment-ordered
    const int KS = kpad[r] >> 5;
    int frag = local >> 9;
    int within = local & 511;
    int lane = within >> 3;
    int e = within & 7;
    int colTile = frag / KS;
    int ks = frag - colTile * KS;
    int col = colTile * 16 + (lane & 15);
    int k = ks * 32 + (lane >> 4) * 8 + e;
    v = (k < ksrc[r]) ? srcs[r][col * ksrc[r] + k] : 0.0f;
  }
  g_w[idx] = f2bfu(v);
}

// ---- fused MLP ----
// Block: 256 threads = 4 waves, 64 rows. LDS: H [64][256] + Xb [64][64],
// both XOR-swizzled at 16B-slot granularity (slot' = slot ^ (row&7)) so
// power-of-2 strides are bank-conflict-free. Total 40960 B -> 4 blocks/CU.
// After L5, Xb region is reused to stage d (cols 0..31) for L9.
// MFMA 16x16x32 bf16, C/D: col=lane&15, row=(lane>>4)*4+i (m89-verified).

// A-read of logical (row, kstep kk): slot = 4*kk + l4 (one 16B slot), addr =
// row*stride + ((slot ^ (row&7))<<3). row&7 == l15&7 for row = rt*16+l15.
template<int KS1, int KS2, int KSTRIDE, int NT, bool INIT>
__device__ __forceinline__ void gemm_compute(
    const unsigned short* A1, int sA1,
    const unsigned short* A2, int sA2,
    const unsigned short* Wp,
    f32x4 (&acc)[4][NT],
    int lane, int wid)
{
  const int l15 = lane & 15;
  const int l4  = lane >> 4;
  const int sx  = l15 & 7;
  const unsigned short* wb = Wp + (size_t)(wid * NT) * KSTRIDE * 512 + lane * 8;

  if (INIT) {
#pragma unroll
    for (int rt = 0; rt < 4; ++rt)
#pragma unroll
      for (int ct = 0; ct < NT; ++ct)
        acc[rt][ct] = (f32x4){0.f, 0.f, 0.f, 0.f};
  }

#pragma unroll
  for (int kk = 0; kk < KS1 + KS2; ++kk) {
    bf16x8 a[4];
    if (kk < KS1) {
      const int soff = ((kk * 4 + l4) ^ sx) << 3;
#pragma unroll
      for (int rt = 0; rt < 4; ++rt)
        a[rt] = *(const bf16x8*)&A1[(rt * 16 + l15) * sA1 + soff];
    } else {
      const int soff = (((kk - KS1) * 4 + l4) ^ sx) << 3;
#pragma unroll
      for (int rt = 0; rt < 4; ++rt)
        a[rt] = *(const bf16x8*)&A2[(rt * 16 + l15) * sA2 + soff];
    }
    bf16x8 b[NT];
#pragma unroll
    for (int ct = 0; ct < NT; ++ct)
      b[ct] = *(const bf16x8*)&wb[(size_t)(ct * KSTRIDE + kk) * 512];
#pragma unroll
    for (int ct = 0; ct < NT; ++ct)
#pragma unroll
      for (int rt = 0; rt < 4; ++rt)
        acc[rt][ct] = __builtin_amdgcn_mfma_f32_16x16x32_bf16(a[rt], b[ct], acc[rt][ct], 0, 0, 0);
  }
}

template<int NT, bool RELU>
__device__ __forceinline__ void store_acc(
    const f32x4 (&acc)[4][NT], const float* bias,
    unsigned short* Out, int sO, int lane, int wid)
{
  const int l15 = lane & 15;
  const int l4  = lane >> 4;
  const int colbase = wid * (NT * 16);
#pragma unroll
  for (int ct = 0; ct < NT; ++ct) {
    const int col = colbase + ct * 16 + l15;
    const int cslot = col >> 3;
    const int coff  = col & 7;
    const float bv = bias[col];
#pragma unroll
    for (int rt = 0; rt < 4; ++rt) {
#pragma unroll
      for (int i = 0; i < 4; ++i) {
        const int row = rt * 16 + l4 * 4 + i;
        float v = acc[rt][ct][i] + bv;
        if (RELU) v = fmaxf(v, 0.0f);
        Out[row * sO + (((cslot ^ (row & 7)) << 3) | coff)] = f2bfu(v);
      }
    }
  }
}

__launch_bounds__(256, 4)
__global__ void nerf_main(const float* __restrict__ x, const float* __restrict__ d,
    const float* b0, const float* b1, const float* b2, const float* b3,
    const float* b4, const float* b5, const float* b6, const float* b7,
    const float* bsig, const float* b8, const float* b9, const float* b10,
    const float* b11, const float* b12, const float* brgb,
    float* __restrict__ out)
{
  __shared__ __align__(16) unsigned short H[64 * 256];   // 32768 B, swizzled
  __shared__ __align__(16) unsigned short Xb[64 * 64];   // 8192 B, swizzled; d after L5

  const int tid = threadIdx.x;
  const int lane = tid & 63;
  const int wid = tid >> 6;
  const int rowbase = blockIdx.x * RTILE;

  // ---- stage x tile (fp32 -> bf16, swizzled write) ----
  {
    const int r = tid >> 2;      // 0..63
    const int sub = tid & 3;
    const int rx = r & 7;
    const float* xr = x + (size_t)(rowbase + r) * 63;
    for (int j = 0; j < 16; ++j) {
      const int c = sub + j * 4;        // 0..63
      const float v = (c < 63) ? xr[c] : 0.0f;
      Xb[r * 64 + ((((c >> 3) ^ rx) << 3) | (c & 7))] = f2bfu(v);
    }
  }
  __syncthreads();

  f32x4 acc4[4][4];
  f32x4 acc2[4][2];

  // L0: reads Xb only -> write H directly (first writer)
  gemm_compute<2,0,2,4,true>(Xb, 64, nullptr, 0, g_w + OFF_W0, acc4, lane, wid);
  store_acc<4,true>(acc4, b0, H, 256, lane, wid);
  __syncthreads();

#define BIG_LAYER(OFFW, BIAS) \
  gemm_compute<8,0,8,4,true>(H, 256, nullptr, 0, g_w + OFFW, acc4, lane, wid); \
  __syncthreads(); \
  store_acc<4,true>(acc4, BIAS, H, 256, lane, wid); \
  __syncthreads();

  BIG_LAYER(OFF_W1, b1)
  BIG_LAYER(OFF_W2, b2)
  BIG_LAYER(OFF_W3, b3)
  BIG_LAYER(OFF_W4, b4)

  // L5: concat [h(256) | x(63)+pad] -> K=320
  gemm_compute<8,2,10,4,true>(H, 256, Xb, 64, g_w + OFF_W5, acc4, lane, wid);
  __syncthreads();
  store_acc<4,true>(acc4, b5, H, 256, lane, wid);
  __syncthreads();

  // ---- Xb is dead now: stage d tile into it (cols 0..31, swizzled) ----
  // Visible to L9 via the L6/L7/L8 barriers.
  {
    const int r = tid >> 2;
    const int sub = tid & 3;
    const int rx = r & 7;
    const float* dr = d + (size_t)(rowbase + r) * 27;
    for (int j = 0; j < 8; ++j) {
      const int c = sub + j * 4;        // 0..31
      const float v = (c < 27) ? dr[c] : 0.0f;
      Xb[r * 64 + ((((c >> 3) ^ rx) << 3) | (c & 7))] = f2bfu(v);
    }
  }

  BIG_LAYER(OFF_W6, b6)
  BIG_LAYER(OFF_W7, b7)

  // ---- sigma head: softplus(h7 @ Wsig + bsig), h7 in H (swizzled reads) ----
  {
    const int r = tid >> 2;
    const int part = tid & 3;
    const int rx = r & 7;
    float s = 0.f;
#pragma unroll
    for (int c = 0; c < 8; ++c) {
      const int chunk = c * 4 + part;
      bf16x8 h = *(const bf16x8*)&H[r * 256 + ((chunk ^ rx) << 3)];
      bf16x8 w = *(const bf16x8*)&g_w[OFF_WSIG + chunk * 8];
#pragma unroll
      for (int e = 0; e < 8; ++e)
        s += (float)h[e] * (float)w[e];
    }
    s += __shfl_xor(s, 1);
    s += __shfl_xor(s, 2);
    if (part == 0) {
      float logit = s + bsig[0];
      float sp = (logit > 0.f) ? (logit + log1pf(expf(-logit))) : log1pf(expf(logit));
      out[3 * NB + rowbase + r] = sp;
    }
  }

  // L8 (bottleneck, no relu)
  gemm_compute<8,0,8,4,true>(H, 256, nullptr, 0, g_w + OFF_W8, acc4, lane, wid);
  __syncthreads();                // also covers sigma-head reads of H
  store_acc<4,false>(acc4, b8, H, 256, lane, wid);
  __syncthreads();

  // L9: concat [h8(256) | d(27)+pad] -> K=288, N=128 (d from Xb region)
  gemm_compute<8,1,9,2,true>(H, 256, Xb, 64, g_w + OFF_W9, acc2, lane, wid);
  __syncthreads();
  store_acc<2,true>(acc2, b9, H, 256, lane, wid);
  __syncthreads();

#define SMALL_LAYER(OFFW, BIAS) \
  gemm_compute<4,0,4,2,true>(H, 256, nullptr, 0, g_w + OFFW, acc2, lane, wid); \
  __syncthreads(); \
  store_acc<2,true>(acc2, BIAS, H, 256, lane, wid); \
  __syncthreads();

  SMALL_LAYER(OFF_W10, b10)
  SMALL_LAYER(OFF_W11, b11)
  SMALL_LAYER(OFF_W12, b12)

  // ---- rgb head: sigmoid(h12 @ Wrgb + brgb), h12 in H cols 0..127 ----
  if (tid < 192) {
    const int r = tid / 3;
    const int ch = tid - r * 3;
    const int rx = r & 7;
    float s = 0.f;
#pragma unroll
    for (int c = 0; c < 16; ++c) {
      bf16x8 h = *(const bf16x8*)&H[r * 256 + ((c ^ rx) << 3)];
      bf16x8 w = *(const bf16x8*)&g_w[OFF_WRGB + ch * 128 + c * 8];
#pragma unroll
      for (int e = 0; e < 8; ++e)
        s += (float)h[e] * (float)w[e];
    }
    float logit = s + brgb[ch];
    float val = 1.f / (1.f + expf(-logit));
    out[(size_t)(rowbase + r) * 3 + ch] = val;
  }
}

extern "C" void kernel_launch(void* const* d_in, const int* in_sizes, int n_in,
                              void* d_out, int out_size, void* d_ws, size_t ws_size,
                              hipStream_t stream) {
  const float* x    = (const float*)d_in[0];
  const float* dd   = (const float*)d_in[1];
  const float* W0   = (const float*)d_in[2];
  const float* b0   = (const float*)d_in[3];
  const float* W1   = (const float*)d_in[4];
  const float* b1   = (const float*)d_in[5];
  const float* W2   = (const float*)d_in[6];
  const float* b2   = (const float*)d_in[7];
  const float* W3   = (const float*)d_in[8];
  const float* b3   = (const float*)d_in[9];
  const float* W4   = (const float*)d_in[10];
  const float* b4   = (const float*)d_in[11];
  const float* W5   = (const float*)d_in[12];
  const float* b5   = (const float*)d_in[13];
  const float* W6   = (const float*)d_in[14];
  const float* b6   = (const float*)d_in[15];
  const float* W7   = (const float*)d_in[16];
  const float* b7   = (const float*)d_in[17];
  const float* Wsig = (const float*)d_in[18];
  const float* bsig = (const float*)d_in[19];
  const float* W8   = (const float*)d_in[20];
  const float* b8   = (const float*)d_in[21];
  const float* W9   = (const float*)d_in[22];
  const float* b9   = (const float*)d_in[23];
  const float* W10  = (const float*)d_in[24];
  const float* b10  = (const float*)d_in[25];
  const float* W11  = (const float*)d_in[26];
  const float* b11  = (const float*)d_in[27];
  const float* W12  = (const float*)d_in[28];
  const float* b12  = (const float*)d_in[29];
  const float* Wrgb = (const float*)d_in[30];
  const float* brgb = (const float*)d_in[31];

  prep_kernel<<<(WTOTAL + 255) / 256, 256, 0, stream>>>(
      W0, W1, W2, W3, W4, W5, W6, W7, Wsig, W8, W9, W10, W11, W12, Wrgb);

  nerf_main<<<NB / RTILE, 256, 0, stream>>>(
      x, dd, b0, b1, b2, b3, b4, b5, b6, b7, bsig, b8, b9, b10, b11, b12, brgb,
      (float*)d_out);
}

// Round 6
// 935.580 us; speedup vs baseline: 1.0052x; 1.0052x over previous
//
#include <hip/hip_runtime.h>
#include <hip/hip_bf16.h>

#define NB 262144
#define RTILE 64

typedef __bf16 bf16x8 __attribute__((ext_vector_type(8)));
typedef float f32x4 __attribute__((ext_vector_type(4)));

// ---- packed bf16 weight buffer ----
// MFMA layers fragment-ordered: fragment (colTile,ks) at
//   off + ((colTile*KSTRIDE + ks)*64 + lane)*8
// lane's elems: W[col=colTile*16+(lane&15)][k=ks*32+(lane>>4)*8+e].
// Wsig/Wrgb plain row-major.
#define OFF_W0   0        // [256][64]   (K 63->64)
#define OFF_W1   16384    // [256][256]
#define OFF_W2   81920
#define OFF_W3   147456
#define OFF_W4   212992
#define OFF_W5   278528   // [256][320]  (K 319->320)
#define OFF_W6   360448
#define OFF_W7   425984
#define OFF_WSIG 491520   // [1][256] plain
#define OFF_W8   491776   // [256][256]
#define OFF_W9   557312   // [128][288]  (K 283->288)
#define OFF_W10  594176   // [128][128]
#define OFF_W11  610560
#define OFF_W12  626944
#define OFF_WRGB 643328   // [3][128] plain
#define WTOTAL   643712

__device__ __align__(16) unsigned short g_w[WTOTAL];

__device__ __forceinline__ unsigned short f2bfu(float f) {
  __bf16 h = (__bf16)f;
  return __builtin_bit_cast(unsigned short, h);
}

__global__ void prep_kernel(const float* W0, const float* W1, const float* W2,
                            const float* W3, const float* W4, const float* W5,
                            const float* W6, const float* W7, const float* Wsig,
                            const float* W8, const float* W9, const float* W10,
                            const float* W11, const float* W12, const float* Wrgb) {
  const float* srcs[15] = {W0,W1,W2,W3,W4,W5,W6,W7,Wsig,W8,W9,W10,W11,W12,Wrgb};
  const int dsto[16] = {OFF_W0,OFF_W1,OFF_W2,OFF_W3,OFF_W4,OFF_W5,OFF_W6,OFF_W7,
                        OFF_WSIG,OFF_W8,OFF_W9,OFF_W10,OFF_W11,OFF_W12,OFF_WRGB,WTOTAL};
  const int kpad[15] = {64,256,256,256,256,320,256,256,256,256,288,128,128,128,128};
  const int ksrc[15] = {63,256,256,256,256,319,256,256,256,256,283,128,128,128,128};
  int idx = blockIdx.x * blockDim.x + threadIdx.x;
  if (idx >= WTOTAL) return;
  int r = 0;
  for (int i = 1; i < 15; ++i) if (idx >= dsto[i]) r = i;
  int local = idx - dsto[r];
  float v;
  if (r == 8 || r == 14) {             // head weights: plain row-major
    int o = local / kpad[r];
    int k = local - o * kpad[r];
    v = (k < ksrc[r]) ? srcs[r][o * ksrc[r] + k] : 0.0f;
  } else {                             // MFMA layers: fragment-ordered
    const int KS = kpad[r] >> 5;
    int frag = local >> 9;
    int within = local & 511;
    int lane = within >> 3;
    int e = within & 7;
    int colTile = frag / KS;
    int ks = frag - colTile * KS;
    int col = colTile * 16 + (lane & 15);
    int k = ks * 32 + (lane >> 4) * 8 + e;
    v = (k < ksrc[r]) ? srcs[r][col * ksrc[r] + k] : 0.0f;
  }
  g_w[idx] = f2bfu(v);
}

// ---- fused MLP ----
// Block: 256 threads = 4 waves, 64 rows. LDS: H [64][256] + Xb [64][64],
// both XOR-swizzled at 16B-slot granularity (slot' = slot ^ (row&7)) so
// power-of-2 strides are bank-conflict-free. Total 40960 B -> 4 blocks/CU.
// After L5, Xb region is reused to stage d (cols 0..31) for L9.
// amdgpu_waves_per_eu(4,4) pins the allocator at the 4-waves/EU budget
// (128 VGPR) -- round-5 showed launch_bounds alone lets it spill down to
// 64 VGPR chasing unreachable 8-waves/EU occupancy.
// MFMA 16x16x32 bf16, C/D: col=lane&15, row=(lane>>4)*4+i (m89-verified).
template<int KS1, int KS2, int KSTRIDE, int NT, bool INIT>
__device__ __forceinline__ void gemm_compute(
    const unsigned short* A1, int sA1,
    const unsigned short* A2, int sA2,
    const unsigned short* Wp,
    f32x4 (&acc)[4][NT],
    int lane, int wid)
{
  const int l15 = lane & 15;
  const int l4  = lane >> 4;
  const int sx  = l15 & 7;
  const unsigned short* wb = Wp + (size_t)(wid * NT) * KSTRIDE * 512 + lane * 8;

  if (INIT) {
#pragma unroll
    for (int rt = 0; rt < 4; ++rt)
#pragma unroll
      for (int ct = 0; ct < NT; ++ct)
        acc[rt][ct] = (f32x4){0.f, 0.f, 0.f, 0.f};
  }

#pragma unroll
  for (int kk = 0; kk < KS1 + KS2; ++kk) {
    bf16x8 a[4];
    if (kk < KS1) {
      const int soff = ((kk * 4 + l4) ^ sx) << 3;
#pragma unroll
      for (int rt = 0; rt < 4; ++rt)
        a[rt] = *(const bf16x8*)&A1[(rt * 16 + l15) * sA1 + soff];
    } else {
      const int soff = (((kk - KS1) * 4 + l4) ^ sx) << 3;
#pragma unroll
      for (int rt = 0; rt < 4; ++rt)
        a[rt] = *(const bf16x8*)&A2[(rt * 16 + l15) * sA2 + soff];
    }
    bf16x8 b[NT];
#pragma unroll
    for (int ct = 0; ct < NT; ++ct)
      b[ct] = *(const bf16x8*)&wb[(size_t)(ct * KSTRIDE + kk) * 512];
#pragma unroll
    for (int ct = 0; ct < NT; ++ct)
#pragma unroll
      for (int rt = 0; rt < 4; ++rt)
        acc[rt][ct] = __builtin_amdgcn_mfma_f32_16x16x32_bf16(a[rt], b[ct], acc[rt][ct], 0, 0, 0);
  }
}

template<int NT, bool RELU>
__device__ __forceinline__ void store_acc(
    const f32x4 (&acc)[4][NT], const float* bias,
    unsigned short* Out, int sO, int lane, int wid)
{
  const int l15 = lane & 15;
  const int l4  = lane >> 4;
  const int colbase = wid * (NT * 16);
#pragma unroll
  for (int ct = 0; ct < NT; ++ct) {
    const int col = colbase + ct * 16 + l15;
    const int cslot = col >> 3;
    const int coff  = col & 7;
    const float bv = bias[col];
#pragma unroll
    for (int rt = 0; rt < 4; ++rt) {
#pragma unroll
      for (int i = 0; i < 4; ++i) {
        const int row = rt * 16 + l4 * 4 + i;
        float v = acc[rt][ct][i] + bv;
        if (RELU) v = fmaxf(v, 0.0f);
        Out[row * sO + (((cslot ^ (row & 7)) << 3) | coff)] = f2bfu(v);
      }
    }
  }
}

__attribute__((amdgpu_flat_work_group_size(256, 256), amdgpu_waves_per_eu(4, 4)))
__global__ void nerf_main(const float* __restrict__ x, const float* __restrict__ d,
    const float* b0, const float* b1, const float* b2, const float* b3,
    const float* b4, const float* b5, const float* b6, const float* b7,
    const float* bsig, const float* b8, const float* b9, const float* b10,
    const float* b11, const float* b12, const float* brgb,
    float* __restrict__ out)
{
  __shared__ __align__(16) unsigned short H[64 * 256];   // 32768 B, swizzled
  __shared__ __align__(16) unsigned short Xb[64 * 64];   // 8192 B, swizzled; d after L5

  const int tid = threadIdx.x;
  const int lane = tid & 63;
  const int wid = tid >> 6;
  const int rowbase = blockIdx.x * RTILE;

  // ---- stage x tile (fp32 -> bf16, swizzled write) ----
  {
    const int r = tid >> 2;      // 0..63
    const int sub = tid & 3;
    const int rx = r & 7;
    const float* xr = x + (size_t)(rowbase + r) * 63;
#pragma unroll
    for (int j = 0; j < 16; ++j) {
      const int c = sub + j * 4;        // 0..63
      const float v = (c < 63) ? xr[c] : 0.0f;
      Xb[r * 64 + ((((c >> 3) ^ rx) << 3) | (c & 7))] = f2bfu(v);
    }
  }
  __syncthreads();

  f32x4 acc4[4][4];
  f32x4 acc2[4][2];

  // L0: reads Xb only -> write H directly (first writer)
  gemm_compute<2,0,2,4,true>(Xb, 64, nullptr, 0, g_w + OFF_W0, acc4, lane, wid);
  store_acc<4,true>(acc4, b0, H, 256, lane, wid);
  __syncthreads();

#define BIG_LAYER(OFFW, BIAS) \
  gemm_compute<8,0,8,4,true>(H, 256, nullptr, 0, g_w + OFFW, acc4, lane, wid); \
  __syncthreads(); \
  store_acc<4,true>(acc4, BIAS, H, 256, lane, wid); \
  __syncthreads();

  BIG_LAYER(OFF_W1, b1)
  BIG_LAYER(OFF_W2, b2)
  BIG_LAYER(OFF_W3, b3)
  BIG_LAYER(OFF_W4, b4)

  // L5: concat [h(256) | x(63)+pad] -> K=320
  gemm_compute<8,2,10,4,true>(H, 256, Xb, 64, g_w + OFF_W5, acc4, lane, wid);
  __syncthreads();
  store_acc<4,true>(acc4, b5, H, 256, lane, wid);
  __syncthreads();

  // ---- Xb is dead now: stage d tile into it (cols 0..31, swizzled) ----
  // Visible to L9 via the L6/L7/L8 barriers.
  {
    const int r = tid >> 2;
    const int sub = tid & 3;
    const int rx = r & 7;
    const float* dr = d + (size_t)(rowbase + r) * 27;
#pragma unroll
    for (int j = 0; j < 8; ++j) {
      const int c = sub + j * 4;        // 0..31
      const float v = (c < 27) ? dr[c] : 0.0f;
      Xb[r * 64 + ((((c >> 3) ^ rx) << 3) | (c & 7))] = f2bfu(v);
    }
  }

  BIG_LAYER(OFF_W6, b6)
  BIG_LAYER(OFF_W7, b7)

  // ---- sigma head: softplus(h7 @ Wsig + bsig), h7 in H (swizzled reads) ----
  {
    const int r = tid >> 2;
    const int part = tid & 3;
    const int rx = r & 7;
    float s = 0.f;
#pragma unroll
    for (int c = 0; c < 8; ++c) {
      const int chunk = c * 4 + part;
      bf16x8 h = *(const bf16x8*)&H[r * 256 + ((chunk ^ rx) << 3)];
      bf16x8 w = *(const bf16x8*)&g_w[OFF_WSIG + chunk * 8];
#pragma unroll
      for (int e = 0; e < 8; ++e)
        s += (float)h[e] * (float)w[e];
    }
    s += __shfl_xor(s, 1);
    s += __shfl_xor(s, 2);
    if (part == 0) {
      float logit = s + bsig[0];
      float sp = (logit > 0.f) ? (logit + log1pf(expf(-logit))) : log1pf(expf(logit));
      out[3 * NB + rowbase + r] = sp;
    }
  }

  // L8 (bottleneck, no relu)
  gemm_compute<8,0,8,4,true>(H, 256, nullptr, 0, g_w + OFF_W8, acc4, lane, wid);
  __syncthreads();                // also covers sigma-head reads of H
  store_acc<4,false>(acc4, b8, H, 256, lane, wid);
  __syncthreads();

  // L9: concat [h8(256) | d(27)+pad] -> K=288, N=128 (d from Xb region)
  gemm_compute<8,1,9,2,true>(H, 256, Xb, 64, g_w + OFF_W9, acc2, lane, wid);
  __syncthreads();
  store_acc<2,true>(acc2, b9, H, 256, lane, wid);
  __syncthreads();

#define SMALL_LAYER(OFFW, BIAS) \
  gemm_compute<4,0,4,2,true>(H, 256, nullptr, 0, g_w + OFFW, acc2, lane, wid); \
  __syncthreads(); \
  store_acc<2,true>(acc2, BIAS, H, 256, lane, wid); \
  __syncthreads();

  SMALL_LAYER(OFF_W10, b10)
  SMALL_LAYER(OFF_W11, b11)
  SMALL_LAYER(OFF_W12, b12)

  // ---- rgb head: sigmoid(h12 @ Wrgb + brgb), h12 in H cols 0..127 ----
  if (tid < 192) {
    const int r = tid / 3;
    const int ch = tid - r * 3;
    const int rx = r & 7;
    float s = 0.f;
#pragma unroll
    for (int c = 0; c < 16; ++c) {
      bf16x8 h = *(const bf16x8*)&H[r * 256 + ((c ^ rx) << 3)];
      bf16x8 w = *(const bf16x8*)&g_w[OFF_WRGB + ch * 128 + c * 8];
#pragma unroll
      for (int e = 0; e < 8; ++e)
        s += (float)h[e] * (float)w[e];
    }
    float logit = s + brgb[ch];
    float val = 1.f / (1.f + expf(-logit));
    out[(size_t)(rowbase + r) * 3 + ch] = val;
  }
}

extern "C" void kernel_launch(void* const* d_in, const int* in_sizes, int n_in,
                              void* d_out, int out_size, void* d_ws, size_t ws_size,
                              hipStream_t stream) {
  const float* x    = (const float*)d_in[0];
  const float* dd   = (const float*)d_in[1];
  const float* W0   = (const float*)d_in[2];
  const float* b0   = (const float*)d_in[3];
  const float* W1   = (const float*)d_in[4];
  const float* b1   = (const float*)d_in[5];
  const float* W2   = (const float*)d_in[6];
  const float* b2   = (const float*)d_in[7];
  const float* W3   = (const float*)d_in[8];
  const float* b3   = (const float*)d_in[9];
  const float* W4   = (const float*)d_in[10];
  const float* b4   = (const float*)d_in[11];
  const float* W5   = (const float*)d_in[12];
  const float* b5   = (const float*)d_in[13];
  const float* W6   = (const float*)d_in[14];
  const float* b6   = (const float*)d_in[15];
  const float* W7   = (const float*)d_in[16];
  const float* b7   = (const float*)d_in[17];
  const float* Wsig = (const float*)d_in[18];
  const float* bsig = (const float*)d_in[19];
  const float* W8   = (const float*)d_in[20];
  const float* b8   = (const float*)d_in[21];
  const float* W9   = (const float*)d_in[22];
  const float* b9   = (const float*)d_in[23];
  const float* W10  = (const float*)d_in[24];
  const float* b10  = (const float*)d_in[25];
  const float* W11  = (const float*)d_in[26];
  const float* b11  = (const float*)d_in[27];
  const float* W12  = (const float*)d_in[28];
  const float* b12  = (const float*)d_in[29];
  const float* Wrgb = (const float*)d_in[30];
  const float* brgb = (const float*)d_in[31];

  prep_kernel<<<(WTOTAL + 255) / 256, 256, 0, stream>>>(
      W0, W1, W2, W3, W4, W5, W6, W7, Wsig, W8, W9, W10, W11, W12, Wrgb);

  nerf_main<<<NB / RTILE, 256, 0, stream>>>(
      x, dd, b0, b1, b2, b3, b4, b5, b6, b7, bsig, b8, b9, b10, b11, b12, brgb,
      (float*)d_out);
}

// Round 7
// 691.580 us; speedup vs baseline: 1.3599x; 1.3528x over previous
//
#include <hip/hip_runtime.h>
#include <hip/hip_bf16.h>

#define NB 262144
#define RTILE 64

typedef __bf16 bf16x8 __attribute__((ext_vector_type(8)));
typedef float f32x4 __attribute__((ext_vector_type(4)));

// ---- packed bf16 weight buffer ----
// MFMA layers fragment-ordered: fragment (colTile,ks) at
//   off + ((colTile*KSTRIDE + ks)*64 + lane)*8
// lane's elems: W[col=colTile*16+(lane&15)][k=ks*32+(lane>>4)*8+e].
// Wsig/Wrgb plain row-major.
#define OFF_W0   0        // [256][64]   (K 63->64)
#define OFF_W1   16384    // [256][256]
#define OFF_W2   81920
#define OFF_W3   147456
#define OFF_W4   212992
#define OFF_W5   278528   // [256][320]  (K 319->320)
#define OFF_W6   360448
#define OFF_W7   425984
#define OFF_WSIG 491520   // [1][256] plain
#define OFF_W8   491776   // [256][256]
#define OFF_W9   557312   // [128][288]  (K 283->288)
#define OFF_W10  594176   // [128][128]
#define OFF_W11  610560
#define OFF_W12  626944
#define OFF_WRGB 643328   // [3][128] plain
#define WTOTAL   643712

__device__ __align__(16) unsigned short g_w[WTOTAL];

__device__ __forceinline__ unsigned short f2bfu(float f) {
  __bf16 h = (__bf16)f;
  return __builtin_bit_cast(unsigned short, h);
}

__global__ void prep_kernel(const float* W0, const float* W1, const float* W2,
                            const float* W3, const float* W4, const float* W5,
                            const float* W6, const float* W7, const float* Wsig,
                            const float* W8, const float* W9, const float* W10,
                            const float* W11, const float* W12, const float* Wrgb) {
  const float* srcs[15] = {W0,W1,W2,W3,W4,W5,W6,W7,Wsig,W8,W9,W10,W11,W12,Wrgb};
  const int dsto[16] = {OFF_W0,OFF_W1,OFF_W2,OFF_W3,OFF_W4,OFF_W5,OFF_W6,OFF_W7,
                        OFF_WSIG,OFF_W8,OFF_W9,OFF_W10,OFF_W11,OFF_W12,OFF_WRGB,WTOTAL};
  const int kpad[15] = {64,256,256,256,256,320,256,256,256,256,288,128,128,128,128};
  const int ksrc[15] = {63,256,256,256,256,319,256,256,256,256,283,128,128,128,128};
  int idx = blockIdx.x * blockDim.x + threadIdx.x;
  if (idx >= WTOTAL) return;
  int r = 0;
  for (int i = 1; i < 15; ++i) if (idx >= dsto[i]) r = i;
  int local = idx - dsto[r];
  float v;
  if (r == 8 || r == 14) {             // head weights: plain row-major
    int o = local / kpad[r];
    int k = local - o * kpad[r];
    v = (k < ksrc[r]) ? srcs[r][o * ksrc[r] + k] : 0.0f;
  } else {                             // MFMA layers: fragment-ordered
    const int KS = kpad[r] >> 5;
    int frag = local >> 9;
    int within = local & 511;
    int lane = within >> 3;
    int e = within & 7;
    int colTile = frag / KS;
    int ks = frag - colTile * KS;
    int col = colTile * 16 + (lane & 15);
    int k = ks * 32 + (lane >> 4) * 8 + e;
    v = (k < ksrc[r]) ? srcs[r][col * ksrc[r] + k] : 0.0f;
  }
  g_w[idx] = f2bfu(v);
}

// ---- fused MLP ----
// Block: 256 threads = 4 waves, 64 rows. LDS: H [64][256] + Xb [64][64],
// both XOR-swizzled at 16B-slot granularity (slot' = slot ^ (row&7)) so
// power-of-2 strides are bank-conflict-free. Total 40960 B -> hardware can
// fit 4 blocks/CU. After L5, Xb region is reused to stage d for L9.
// __launch_bounds__(256,3): min 3 waves/EU -> VGPR budget 168. Round 5/6
// showed that declaring min=4 (budget 128) with this swizzled code makes
// the allocator fall to 64 VGPRs with wholesale scratch spill (2 GB HBM
// traffic). With budget 168 it should allocate ~100-120; anything <=128
// still lets the hardware reach 4 blocks/CU (LDS permits exactly 4).
// MFMA 16x16x32 bf16, C/D: col=lane&15, row=(lane>>4)*4+i (m89-verified).
template<int KS1, int KS2, int KSTRIDE, int NT, bool INIT>
__device__ __forceinline__ void gemm_compute(
    const unsigned short* A1, int sA1,
    const unsigned short* A2, int sA2,
    const unsigned short* Wp,
    f32x4 (&acc)[4][NT],
    int lane, int wid)
{
  const int l15 = lane & 15;
  const int l4  = lane >> 4;
  const int sx  = l15 & 7;
  const unsigned short* wb = Wp + (size_t)(wid * NT) * KSTRIDE * 512 + lane * 8;

  if (INIT) {
#pragma unroll
    for (int rt = 0; rt < 4; ++rt)
#pragma unroll
      for (int ct = 0; ct < NT; ++ct)
        acc[rt][ct] = (f32x4){0.f, 0.f, 0.f, 0.f};
  }

#pragma unroll
  for (int kk = 0; kk < KS1 + KS2; ++kk) {
    bf16x8 a[4];
    if (kk < KS1) {
      const int soff = ((kk * 4 + l4) ^ sx) << 3;
#pragma unroll
      for (int rt = 0; rt < 4; ++rt)
        a[rt] = *(const bf16x8*)&A1[(rt * 16 + l15) * sA1 + soff];
    } else {
      const int soff = (((kk - KS1) * 4 + l4) ^ sx) << 3;
#pragma unroll
      for (int rt = 0; rt < 4; ++rt)
        a[rt] = *(const bf16x8*)&A2[(rt * 16 + l15) * sA2 + soff];
    }
    bf16x8 b[NT];
#pragma unroll
    for (int ct = 0; ct < NT; ++ct)
      b[ct] = *(const bf16x8*)&wb[(size_t)(ct * KSTRIDE + kk) * 512];
#pragma unroll
    for (int ct = 0; ct < NT; ++ct)
#pragma unroll
      for (int rt = 0; rt < 4; ++rt)
        acc[rt][ct] = __builtin_amdgcn_mfma_f32_16x16x32_bf16(a[rt], b[ct], acc[rt][ct], 0, 0, 0);
  }
}

template<int NT, bool RELU>
__device__ __forceinline__ void store_acc(
    const f32x4 (&acc)[4][NT], const float* bias,
    unsigned short* Out, int sO, int lane, int wid)
{
  const int l15 = lane & 15;
  const int l4  = lane >> 4;
  const int colbase = wid * (NT * 16);
#pragma unroll
  for (int ct = 0; ct < NT; ++ct) {
    const int col = colbase + ct * 16 + l15;
    const int cslot = col >> 3;
    const int coff  = col & 7;
    const float bv = bias[col];
#pragma unroll
    for (int rt = 0; rt < 4; ++rt) {
#pragma unroll
      for (int i = 0; i < 4; ++i) {
        const int row = rt * 16 + l4 * 4 + i;
        float v = acc[rt][ct][i] + bv;
        if (RELU) v = fmaxf(v, 0.0f);
        Out[row * sO + (((cslot ^ (row & 7)) << 3) | coff)] = f2bfu(v);
      }
    }
  }
}

__launch_bounds__(256, 3)
__global__ void nerf_main(const float* __restrict__ x, const float* __restrict__ d,
    const float* b0, const float* b1, const float* b2, const float* b3,
    const float* b4, const float* b5, const float* b6, const float* b7,
    const float* bsig, const float* b8, const float* b9, const float* b10,
    const float* b11, const float* b12, const float* brgb,
    float* __restrict__ out)
{
  __shared__ __align__(16) unsigned short H[64 * 256];   // 32768 B, swizzled
  __shared__ __align__(16) unsigned short Xb[64 * 64];   // 8192 B, swizzled; d after L5

  const int tid = threadIdx.x;
  const int lane = tid & 63;
  const int wid = tid >> 6;
  const int rowbase = blockIdx.x * RTILE;

  // ---- stage x tile (fp32 -> bf16, swizzled write) ----
  {
    const int r = tid >> 2;      // 0..63
    const int sub = tid & 3;
    const int rx = r & 7;
    const float* xr = x + (size_t)(rowbase + r) * 63;
#pragma unroll
    for (int j = 0; j < 16; ++j) {
      const int c = sub + j * 4;        // 0..63
      const float v = (c < 63) ? xr[c] : 0.0f;
      Xb[r * 64 + ((((c >> 3) ^ rx) << 3) | (c & 7))] = f2bfu(v);
    }
  }
  __syncthreads();

  f32x4 acc4[4][4];
  f32x4 acc2[4][2];

  // L0: reads Xb only -> write H directly (first writer)
  gemm_compute<2,0,2,4,true>(Xb, 64, nullptr, 0, g_w + OFF_W0, acc4, lane, wid);
  store_acc<4,true>(acc4, b0, H, 256, lane, wid);
  __syncthreads();

#define BIG_LAYER(OFFW, BIAS) \
  gemm_compute<8,0,8,4,true>(H, 256, nullptr, 0, g_w + OFFW, acc4, lane, wid); \
  __syncthreads(); \
  store_acc<4,true>(acc4, BIAS, H, 256, lane, wid); \
  __syncthreads();

  BIG_LAYER(OFF_W1, b1)
  BIG_LAYER(OFF_W2, b2)
  BIG_LAYER(OFF_W3, b3)
  BIG_LAYER(OFF_W4, b4)

  // L5: concat [h(256) | x(63)+pad] -> K=320
  gemm_compute<8,2,10,4,true>(H, 256, Xb, 64, g_w + OFF_W5, acc4, lane, wid);
  __syncthreads();
  store_acc<4,true>(acc4, b5, H, 256, lane, wid);
  __syncthreads();

  // ---- Xb is dead now: stage d tile into it (cols 0..31, swizzled) ----
  // Visible to L9 via the L6/L7/L8 barriers.
  {
    const int r = tid >> 2;
    const int sub = tid & 3;
    const int rx = r & 7;
    const float* dr = d + (size_t)(rowbase + r) * 27;
#pragma unroll
    for (int j = 0; j < 8; ++j) {
      const int c = sub + j * 4;        // 0..31
      const float v = (c < 27) ? dr[c] : 0.0f;
      Xb[r * 64 + ((((c >> 3) ^ rx) << 3) | (c & 7))] = f2bfu(v);
    }
  }

  BIG_LAYER(OFF_W6, b6)
  BIG_LAYER(OFF_W7, b7)

  // ---- sigma head: softplus(h7 @ Wsig + bsig), h7 in H (swizzled reads) ----
  {
    const int r = tid >> 2;
    const int part = tid & 3;
    const int rx = r & 7;
    float s = 0.f;
#pragma unroll
    for (int c = 0; c < 8; ++c) {
      const int chunk = c * 4 + part;
      bf16x8 h = *(const bf16x8*)&H[r * 256 + ((chunk ^ rx) << 3)];
      bf16x8 w = *(const bf16x8*)&g_w[OFF_WSIG + chunk * 8];
#pragma unroll
      for (int e = 0; e < 8; ++e)
        s += (float)h[e] * (float)w[e];
    }
    s += __shfl_xor(s, 1);
    s += __shfl_xor(s, 2);
    if (part == 0) {
      float logit = s + bsig[0];
      float sp = (logit > 0.f) ? (logit + log1pf(expf(-logit))) : log1pf(expf(logit));
      out[3 * NB + rowbase + r] = sp;
    }
  }

  // L8 (bottleneck, no relu)
  gemm_compute<8,0,8,4,true>(H, 256, nullptr, 0, g_w + OFF_W8, acc4, lane, wid);
  __syncthreads();                // also covers sigma-head reads of H
  store_acc<4,false>(acc4, b8, H, 256, lane, wid);
  __syncthreads();

  // L9: concat [h8(256) | d(27)+pad] -> K=288, N=128 (d from Xb region)
  gemm_compute<8,1,9,2,true>(H, 256, Xb, 64, g_w + OFF_W9, acc2, lane, wid);
  __syncthreads();
  store_acc<2,true>(acc2, b9, H, 256, lane, wid);
  __syncthreads();

#define SMALL_LAYER(OFFW, BIAS) \
  gemm_compute<4,0,4,2,true>(H, 256, nullptr, 0, g_w + OFFW, acc2, lane, wid); \
  __syncthreads(); \
  store_acc<2,true>(acc2, BIAS, H, 256, lane, wid); \
  __syncthreads();

  SMALL_LAYER(OFF_W10, b10)
  SMALL_LAYER(OFF_W11, b11)
  SMALL_LAYER(OFF_W12, b12)

  // ---- rgb head: sigmoid(h12 @ Wrgb + brgb), h12 in H cols 0..127 ----
  if (tid < 192) {
    const int r = tid / 3;
    const int ch = tid - r * 3;
    const int rx = r & 7;
    float s = 0.f;
#pragma unroll
    for (int c = 0; c < 16; ++c) {
      bf16x8 h = *(const bf16x8*)&H[r * 256 + ((c ^ rx) << 3)];
      bf16x8 w = *(const bf16x8*)&g_w[OFF_WRGB + ch * 128 + c * 8];
#pragma unroll
      for (int e = 0; e < 8; ++e)
        s += (float)h[e] * (float)w[e];
    }
    float logit = s + brgb[ch];
    float val = 1.f / (1.f + expf(-logit));
    out[(size_t)(rowbase + r) * 3 + ch] = val;
  }
}

extern "C" void kernel_launch(void* const* d_in, const int* in_sizes, int n_in,
                              void* d_out, int out_size, void* d_ws, size_t ws_size,
                              hipStream_t stream) {
  const float* x    = (const float*)d_in[0];
  const float* dd   = (const float*)d_in[1];
  const float* W0   = (const float*)d_in[2];
  const float* b0   = (const float*)d_in[3];
  const float* W1   = (const float*)d_in[4];
  const float* b1   = (const float*)d_in[5];
  const float* W2   = (const float*)d_in[6];
  const float* b2   = (const float*)d_in[7];
  const float* W3   = (const float*)d_in[8];
  const float* b3   = (const float*)d_in[9];
  const float* W4   = (const float*)d_in[10];
  const float* b4   = (const float*)d_in[11];
  const float* W5   = (const float*)d_in[12];
  const float* b5   = (const float*)d_in[13];
  const float* W6   = (const float*)d_in[14];
  const float* b6   = (const float*)d_in[15];
  const float* W7   = (const float*)d_in[16];
  const float* b7   = (const float*)d_in[17];
  const float* Wsig = (const float*)d_in[18];
  const float* bsig = (const float*)d_in[19];
  const float* W8   = (const float*)d_in[20];
  const float* b8   = (const float*)d_in[21];
  const float* W9   = (const float*)d_in[22];
  const float* b9   = (const float*)d_in[23];
  const float* W10  = (const float*)d_in[24];
  const float* b10  = (const float*)d_in[25];
  const float* W11  = (const float*)d_in[26];
  const float* b11  = (const float*)d_in[27];
  const float* W12  = (const float*)d_in[28];
  const float* b12  = (const float*)d_in[29];
  const float* Wrgb = (const float*)d_in[30];
  const float* brgb = (const float*)d_in[31];

  prep_kernel<<<(WTOTAL + 255) / 256, 256, 0, stream>>>(
      W0, W1, W2, W3, W4, W5, W6, W7, Wsig, W8, W9, W10, W11, W12, Wrgb);

  nerf_main<<<NB / RTILE, 256, 0, stream>>>(
      x, dd, b0, b1, b2, b3, b4, b5, b6, b7, bsig, b8, b9, b10, b11, b12, brgb,
      (float*)d_out);
}

// Round 8
// 487.150 us; speedup vs baseline: 1.9305x; 1.4196x over previous
//
#include <hip/hip_runtime.h>
#include <hip/hip_bf16.h>

#define NB 262144
#define RTILE 64

typedef __bf16 bf16x8 __attribute__((ext_vector_type(8)));
typedef float f32x4 __attribute__((ext_vector_type(4)));

// ---- packed bf16 weight buffer ----
// MFMA layers fragment-ordered: fragment (colTile,ks) at
//   off + ((colTile*KSTRIDE + ks)*64 + lane)*8
// lane's elems: W[col=colTile*16+(lane&15)][k=ks*32+(lane>>4)*8+e].
// Wsig/Wrgb plain row-major.
#define OFF_W0   0        // [256][64]   (K 63->64)
#define OFF_W1   16384    // [256][256]
#define OFF_W2   81920
#define OFF_W3   147456
#define OFF_W4   212992
#define OFF_W5   278528   // [256][320]  (K 319->320; ks 8,9 = x)
#define OFF_W6   360448
#define OFF_W7   425984
#define OFF_WSIG 491520   // [1][256] plain
#define OFF_W8   491776   // [256][256]
#define OFF_W9   557312   // [128][288]  (K 283->288; ks 8 = d)
#define OFF_W10  594176   // [128][128]
#define OFF_W11  610560
#define OFF_W12  626944
#define OFF_WRGB 643328   // [3][128] plain
#define WTOTAL   643712

__device__ __align__(16) unsigned short g_w[WTOTAL];

__device__ __forceinline__ unsigned short f2bfu(float f) {
  __bf16 h = (__bf16)f;
  return __builtin_bit_cast(unsigned short, h);
}
__device__ __forceinline__ float bfu2f(unsigned short u) {
  return (float)__builtin_bit_cast(__bf16, u);
}

__global__ void prep_kernel(const float* W0, const float* W1, const float* W2,
                            const float* W3, const float* W4, const float* W5,
                            const float* W6, const float* W7, const float* Wsig,
                            const float* W8, const float* W9, const float* W10,
                            const float* W11, const float* W12, const float* Wrgb) {
  const float* srcs[15] = {W0,W1,W2,W3,W4,W5,W6,W7,Wsig,W8,W9,W10,W11,W12,Wrgb};
  const int dsto[16] = {OFF_W0,OFF_W1,OFF_W2,OFF_W3,OFF_W4,OFF_W5,OFF_W6,OFF_W7,
                        OFF_WSIG,OFF_W8,OFF_W9,OFF_W10,OFF_W11,OFF_W12,OFF_WRGB,WTOTAL};
  const int kpad[15] = {64,256,256,256,256,320,256,256,256,256,288,128,128,128,128};
  const int ksrc[15] = {63,256,256,256,256,319,256,256,256,256,283,128,128,128,128};
  int idx = blockIdx.x * blockDim.x + threadIdx.x;
  if (idx >= WTOTAL) return;
  int r = 0;
  for (int i = 1; i < 15; ++i) if (idx >= dsto[i]) r = i;
  int local = idx - dsto[r];
  float v;
  if (r == 8 || r == 14) {             // head weights: plain row-major
    int o = local / kpad[r];
    int k = local - o * kpad[r];
    v = (k < ksrc[r]) ? srcs[r][o * ksrc[r] + k] : 0.0f;
  } else {                             // MFMA layers: fragment-ordered
    const int KS = kpad[r] >> 5;
    int frag = local >> 9;
    int within = local & 511;
    int lane = within >> 3;
    int e = within & 7;
    int colTile = frag / KS;
    int ks = frag - colTile * KS;
    int col = colTile * 16 + (lane & 15);
    int k = ks * 32 + (lane >> 4) * 8 + e;
    v = (k < ksrc[r]) ? srcs[r][col * ksrc[r] + k] : 0.0f;
  }
  g_w[idx] = f2bfu(v);
}

// ---- fused MLP ----
// Block: 256 threads = 4 waves, 64 rows. LDS: H [64][264] (padded, round-3
// proven codegen) + Db [64][40] = 38912 B -> 4 blocks/CU. x is NOT staged:
// L0/L5 build their x A-fragments straight from global into registers
// (16 fp32/lane, twice) -- x re-read costs ~66 MB HBM (~10 us), cheaper
// than the 4th resident block is worth.
// MFMA 16x16x32 bf16, C/D: col=lane&15, row=(lane>>4)*4+i (m89-verified).
template<int KS1, int KS2, int KSTRIDE, int NT, bool INIT>
__device__ __forceinline__ void gemm_compute(
    const unsigned short* A1, int sA1,
    const unsigned short* A2, int sA2,
    const unsigned short* Wp,
    f32x4 (&acc)[4][NT],
    int lane, int wid)
{
  const int l15 = lane & 15;
  const int l4  = lane >> 4;
  const unsigned short* wb = Wp + (size_t)(wid * NT) * KSTRIDE * 512 + lane * 8;

  if (INIT) {
#pragma unroll
    for (int rt = 0; rt < 4; ++rt)
#pragma unroll
      for (int ct = 0; ct < NT; ++ct)
        acc[rt][ct] = (f32x4){0.f, 0.f, 0.f, 0.f};
  }

#pragma unroll
  for (int kk = 0; kk < KS1 + KS2; ++kk) {
    bf16x8 a[4];
    if (kk < KS1) {
      const int koff = kk * 32 + l4 * 8;
#pragma unroll
      for (int rt = 0; rt < 4; ++rt)
        a[rt] = *(const bf16x8*)&A1[(rt * 16 + l15) * sA1 + koff];
    } else {
      const int koff = (kk - KS1) * 32 + l4 * 8;
#pragma unroll
      for (int rt = 0; rt < 4; ++rt)
        a[rt] = *(const bf16x8*)&A2[(rt * 16 + l15) * sA2 + koff];
    }
    bf16x8 b[NT];
#pragma unroll
    for (int ct = 0; ct < NT; ++ct)
      b[ct] = *(const bf16x8*)&wb[(size_t)(ct * KSTRIDE + kk) * 512];
#pragma unroll
    for (int ct = 0; ct < NT; ++ct)
#pragma unroll
      for (int rt = 0; rt < 4; ++rt)
        acc[rt][ct] = __builtin_amdgcn_mfma_f32_16x16x32_bf16(a[rt], b[ct], acc[rt][ct], 0, 0, 0);
  }
}

// One K-step whose A-fragments are already in registers; B from packed weights.
// wks = Wp + ((wid*NT)*KSTRIDE + ks)*512 + lane*8.
template<int KSTRIDE, int NT>
__device__ __forceinline__ void mfma_reg_kstep(
    const bf16x8 (&a)[4], const unsigned short* wks, f32x4 (&acc)[4][NT])
{
  bf16x8 b[NT];
#pragma unroll
  for (int ct = 0; ct < NT; ++ct)
    b[ct] = *(const bf16x8*)&wks[(size_t)ct * KSTRIDE * 512];
#pragma unroll
  for (int ct = 0; ct < NT; ++ct)
#pragma unroll
    for (int rt = 0; rt < 4; ++rt)
      acc[rt][ct] = __builtin_amdgcn_mfma_f32_16x16x32_bf16(a[rt], b[ct], acc[rt][ct], 0, 0, 0);
}

// Build A-fragments for kstep starting at k0 directly from a global fp32
// row-major [.., ncols] matrix (rows rowbase+rt*16+l15), zero-padded k>=ncols.
__device__ __forceinline__ void load_row_frags(
    const float* __restrict__ src, int ncols, int rowbase,
    int k0, int l15, int l4, bf16x8 (&a)[4])
{
#pragma unroll
  for (int rt = 0; rt < 4; ++rt) {
    const float* sr = src + (size_t)(rowbase + rt * 16 + l15) * ncols;
    bf16x8 v;
#pragma unroll
    for (int e = 0; e < 8; ++e) {
      const int k = k0 + l4 * 8 + e;
      v[e] = (k < ncols) ? (__bf16)sr[k] : (__bf16)0.0f;
    }
    a[rt] = v;
  }
}

template<int NT, bool RELU>
__device__ __forceinline__ void store_acc(
    const f32x4 (&acc)[4][NT], const float* bias,
    unsigned short* Out, int sO, int lane, int wid)
{
  const int l15 = lane & 15;
  const int l4  = lane >> 4;
  const int colbase = wid * (NT * 16);
#pragma unroll
  for (int ct = 0; ct < NT; ++ct) {
    const int col = colbase + ct * 16 + l15;
    const float bv = bias[col];
#pragma unroll
    for (int rt = 0; rt < 4; ++rt) {
#pragma unroll
      for (int i = 0; i < 4; ++i) {
        const int row = rt * 16 + l4 * 4 + i;
        float v = acc[rt][ct][i] + bv;
        if (RELU) v = fmaxf(v, 0.0f);
        Out[row * sO + col] = f2bfu(v);
      }
    }
  }
}

__launch_bounds__(256, 3)
__global__ void nerf_main(const float* __restrict__ x, const float* __restrict__ d,
    const float* b0, const float* b1, const float* b2, const float* b3,
    const float* b4, const float* b5, const float* b6, const float* b7,
    const float* bsig, const float* b8, const float* b9, const float* b10,
    const float* b11, const float* b12, const float* brgb,
    float* __restrict__ out)
{
  __shared__ unsigned short H[64 * 264];   // 33792 B, padded stride (round-3 proven)
  __shared__ unsigned short Db[64 * 40];   // 5120 B; cols 27..31 zeroed

  const int tid = threadIdx.x;
  const int lane = tid & 63;
  const int wid = tid >> 6;
  const int l15 = lane & 15;
  const int l4  = lane >> 4;
  const int rowbase = blockIdx.x * RTILE;

  // ---- stage d tile (fp32 -> bf16) ----
  {
    const int r = tid >> 2;      // 0..63
    const int sub = tid & 3;
    const float* dr = d + (size_t)(rowbase + r) * 27;
    for (int j = 0; j < 8; ++j) {
      const int c = sub + j * 4;        // 0..31
      Db[r * 40 + c] = (c < 27) ? f2bfu(dr[c]) : (unsigned short)0;
    }
  }
  __syncthreads();

  f32x4 acc4[4][4];
  f32x4 acc2[4][2];

  // ---- L0: x from global registers, 2 ksteps ----
  {
#pragma unroll
    for (int rt = 0; rt < 4; ++rt)
#pragma unroll
      for (int ct = 0; ct < 4; ++ct)
        acc4[rt][ct] = (f32x4){0.f, 0.f, 0.f, 0.f};
    bf16x8 ax[4];
    load_row_frags(x, 63, rowbase, 0, l15, l4, ax);
    mfma_reg_kstep<2,4>(ax, g_w + OFF_W0 + ((size_t)(wid * 4) * 2 + 0) * 512 + lane * 8, acc4);
    load_row_frags(x, 63, rowbase, 32, l15, l4, ax);
    mfma_reg_kstep<2,4>(ax, g_w + OFF_W0 + ((size_t)(wid * 4) * 2 + 1) * 512 + lane * 8, acc4);
  }
  store_acc<4,true>(acc4, b0, H, 264, lane, wid);
  __syncthreads();

#define BIG_LAYER(OFFW, BIAS) \
  gemm_compute<8,0,8,4,true>(H, 264, nullptr, 0, g_w + OFFW, acc4, lane, wid); \
  __syncthreads(); \
  store_acc<4,true>(acc4, BIAS, H, 264, lane, wid); \
  __syncthreads();

  BIG_LAYER(OFF_W1, b1)
  BIG_LAYER(OFF_W2, b2)
  BIG_LAYER(OFF_W3, b3)
  BIG_LAYER(OFF_W4, b4)

  // ---- L5: concat [h(256) | x(63)+pad]: 8 LDS ksteps + 2 global-x ksteps ----
  gemm_compute<8,0,10,4,true>(H, 264, nullptr, 0, g_w + OFF_W5, acc4, lane, wid);
  {
    bf16x8 ax[4];
    load_row_frags(x, 63, rowbase, 0, l15, l4, ax);
    mfma_reg_kstep<10,4>(ax, g_w + OFF_W5 + ((size_t)(wid * 4) * 10 + 8) * 512 + lane * 8, acc4);
    load_row_frags(x, 63, rowbase, 32, l15, l4, ax);
    mfma_reg_kstep<10,4>(ax, g_w + OFF_W5 + ((size_t)(wid * 4) * 10 + 9) * 512 + lane * 8, acc4);
  }
  __syncthreads();
  store_acc<4,true>(acc4, b5, H, 264, lane, wid);
  __syncthreads();

  BIG_LAYER(OFF_W6, b6)
  BIG_LAYER(OFF_W7, b7)

  // ---- sigma head: softplus(h7 @ Wsig + bsig), h7 in H ----
  {
    const int r = tid >> 2;
    const int part = tid & 3;
    float s = 0.f;
    const unsigned short* wrow = g_w + OFF_WSIG + part * 64;
    const unsigned short* hrow = &H[r * 264 + part * 64];
#pragma unroll 8
    for (int k = 0; k < 64; ++k)
      s += bfu2f(hrow[k]) * bfu2f(wrow[k]);
    s += __shfl_xor(s, 1);
    s += __shfl_xor(s, 2);
    if (part == 0) {
      float logit = s + bsig[0];
      float sp = (logit > 0.f) ? (logit + log1pf(expf(-logit))) : log1pf(expf(logit));
      out[3 * NB + rowbase + r] = sp;
    }
  }

  // L8 (bottleneck, no relu)
  gemm_compute<8,0,8,4,true>(H, 264, nullptr, 0, g_w + OFF_W8, acc4, lane, wid);
  __syncthreads();                // also covers sigma-head reads of H
  store_acc<4,false>(acc4, b8, H, 264, lane, wid);
  __syncthreads();

  // L9: concat [h8(256) | d(27)+pad] -> K=288, N=128 (d from Db)
  gemm_compute<8,1,9,2,true>(H, 264, Db, 40, g_w + OFF_W9, acc2, lane, wid);
  __syncthreads();
  store_acc<2,true>(acc2, b9, H, 264, lane, wid);
  __syncthreads();

#define SMALL_LAYER(OFFW, BIAS) \
  gemm_compute<4,0,4,2,true>(H, 264, nullptr, 0, g_w + OFFW, acc2, lane, wid); \
  __syncthreads(); \
  store_acc<2,true>(acc2, BIAS, H, 264, lane, wid); \
  __syncthreads();

  SMALL_LAYER(OFF_W10, b10)
  SMALL_LAYER(OFF_W11, b11)
  SMALL_LAYER(OFF_W12, b12)

  // ---- rgb head: sigmoid(h12 @ Wrgb + brgb), h12 in H cols 0..127 ----
  if (tid < 192) {
    const int r = tid / 3;
    const int ch = tid - r * 3;
    float s = 0.f;
    const unsigned short* wrow = g_w + OFF_WRGB + ch * 128;
#pragma unroll 8
    for (int k = 0; k < 128; ++k)
      s += bfu2f(H[r * 264 + k]) * bfu2f(wrow[k]);
    float logit = s + brgb[ch];
    float val = 1.f / (1.f + expf(-logit));
    out[(size_t)(rowbase + r) * 3 + ch] = val;
  }
}

extern "C" void kernel_launch(void* const* d_in, const int* in_sizes, int n_in,
                              void* d_out, int out_size, void* d_ws, size_t ws_size,
                              hipStream_t stream) {
  const float* x    = (const float*)d_in[0];
  const float* dd   = (const float*)d_in[1];
  const float* W0   = (const float*)d_in[2];
  const float* b0   = (const float*)d_in[3];
  const float* W1   = (const float*)d_in[4];
  const float* b1   = (const float*)d_in[5];
  const float* W2   = (const float*)d_in[6];
  const float* b2   = (const float*)d_in[7];
  const float* W3   = (const float*)d_in[8];
  const float* b3   = (const float*)d_in[9];
  const float* W4   = (const float*)d_in[10];
  const float* b4   = (const float*)d_in[11];
  const float* W5   = (const float*)d_in[12];
  const float* b5   = (const float*)d_in[13];
  const float* W6   = (const float*)d_in[14];
  const float* b6   = (const float*)d_in[15];
  const float* W7   = (const float*)d_in[16];
  const float* b7   = (const float*)d_in[17];
  const float* Wsig = (const float*)d_in[18];
  const float* bsig = (const float*)d_in[19];
  const float* W8   = (const float*)d_in[20];
  const float* b8   = (const float*)d_in[21];
  const float* W9   = (const float*)d_in[22];
  const float* b9   = (const float*)d_in[23];
  const float* W10  = (const float*)d_in[24];
  const float* b10  = (const float*)d_in[25];
  const float* W11  = (const float*)d_in[26];
  const float* b11  = (const float*)d_in[27];
  const float* W12  = (const float*)d_in[28];
  const float* b12  = (const float*)d_in[29];
  const float* Wrgb = (const float*)d_in[30];
  const float* brgb = (const float*)d_in[31];

  prep_kernel<<<(WTOTAL + 255) / 256, 256, 0, stream>>>(
      W0, W1, W2, W3, W4, W5, W6, W7, Wsig, W8, W9, W10, W11, W12, Wrgb);

  nerf_main<<<NB / RTILE, 256, 0, stream>>>(
      x, dd, b0, b1, b2, b3, b4, b5, b6, b7, bsig, b8, b9, b10, b11, b12, brgb,
      (float*)d_out);
}

// Round 9
// 331.403 us; speedup vs baseline: 2.8378x; 1.4700x over previous
//
#include <hip/hip_runtime.h>
#include <hip/hip_bf16.h>

#define NB 262144
#define RTILE 64

typedef __bf16 bf16x8 __attribute__((ext_vector_type(8)));
typedef float f32x4 __attribute__((ext_vector_type(4)));

// ---- packed bf16 weight buffer ----
// MFMA layers fragment-ordered: fragment (colTile,ks) at
//   off + ((colTile*KSTRIDE + ks)*64 + lane)*8
// lane's elems: W[col=colTile*16+(lane&15)][k=ks*32+(lane>>4)*8+e].
// Wsig/Wrgb plain row-major.
#define OFF_W0   0        // [256][64]   (K 63->64)
#define OFF_W1   16384    // [256][256]
#define OFF_W2   81920
#define OFF_W3   147456
#define OFF_W4   212992
#define OFF_W5   278528   // [256][320]  (K 319->320; ks 8,9 = x)
#define OFF_W6   360448
#define OFF_W7   425984
#define OFF_WSIG 491520   // [1][256] plain
#define OFF_W8   491776   // [256][256]
#define OFF_W9   557312   // [128][288]  (K 283->288; ks 8 = d)
#define OFF_W10  594176   // [128][128]
#define OFF_W11  610560
#define OFF_W12  626944
#define OFF_WRGB 643328   // [3][128] plain
#define WTOTAL   643712

__device__ __align__(16) unsigned short g_w[WTOTAL];

__device__ __forceinline__ unsigned short f2bfu(float f) {
  __bf16 h = (__bf16)f;
  return __builtin_bit_cast(unsigned short, h);
}
__device__ __forceinline__ float bfu2f(unsigned short u) {
  return (float)__builtin_bit_cast(__bf16, u);
}

__global__ void prep_kernel(const float* W0, const float* W1, const float* W2,
                            const float* W3, const float* W4, const float* W5,
                            const float* W6, const float* W7, const float* Wsig,
                            const float* W8, const float* W9, const float* W10,
                            const float* W11, const float* W12, const float* Wrgb) {
  const float* srcs[15] = {W0,W1,W2,W3,W4,W5,W6,W7,Wsig,W8,W9,W10,W11,W12,Wrgb};
  const int dsto[16] = {OFF_W0,OFF_W1,OFF_W2,OFF_W3,OFF_W4,OFF_W5,OFF_W6,OFF_W7,
                        OFF_WSIG,OFF_W8,OFF_W9,OFF_W10,OFF_W11,OFF_W12,OFF_WRGB,WTOTAL};
  const int kpad[15] = {64,256,256,256,256,320,256,256,256,256,288,128,128,128,128};
  const int ksrc[15] = {63,256,256,256,256,319,256,256,256,256,283,128,128,128,128};
  int idx = blockIdx.x * blockDim.x + threadIdx.x;
  if (idx >= WTOTAL) return;
  int r = 0;
  for (int i = 1; i < 15; ++i) if (idx >= dsto[i]) r = i;
  int local = idx - dsto[r];
  float v;
  if (r == 8 || r == 14) {             // head weights: plain row-major
    int o = local / kpad[r];
    int k = local - o * kpad[r];
    v = (k < ksrc[r]) ? srcs[r][o * ksrc[r] + k] : 0.0f;
  } else {                             // MFMA layers: fragment-ordered
    const int KS = kpad[r] >> 5;
    int frag = local >> 9;
    int within = local & 511;
    int lane = within >> 3;
    int e = within & 7;
    int colTile = frag / KS;
    int ks = frag - colTile * KS;
    int col = colTile * 16 + (lane & 15);
    int k = ks * 32 + (lane >> 4) * 8 + e;
    v = (k < ksrc[r]) ? srcs[r][col * ksrc[r] + k] : 0.0f;
  }
  g_w[idx] = f2bfu(v);
}

// ---- fused MLP ----
// Round-3 proven structure: 256 threads = 4 waves, 64 rows. LDS: single H
// [64][264] + Xb [64][72] + Db [64][40] = 48128 B -> 3 blocks/CU.
// NEW (round 9): SWAPPED-OPERAND MFMA -- acc = mfma(W_frag, H_frag, acc).
// A/B slot fragment layouts are symmetric, so the C/D mapping transposes to
//   row = rt*16 + (lane&15), col = ct*16 + (lane>>4)*4 + i
// i.e. each lane's 4 acc values are 4 CONSECUTIVE COLUMNS of one row ->
// store packs them into one ds_write_b64 (16 stores/wave/layer vs 64 scalar
// b16 stores that were 4-way bank-conflicted -- the constant 2.3e7 counter).
template<int KS1, int KS2, int KSTRIDE, int NT, bool INIT>
__device__ __forceinline__ void gemm_compute(
    const unsigned short* A1, int sA1,
    const unsigned short* A2, int sA2,
    const unsigned short* Wp,
    f32x4 (&acc)[4][NT],
    int lane, int wid)
{
  const int l15 = lane & 15;
  const int l4  = lane >> 4;
  const unsigned short* wb = Wp + (size_t)(wid * NT) * KSTRIDE * 512 + lane * 8;

  if (INIT) {
#pragma unroll
    for (int rt = 0; rt < 4; ++rt)
#pragma unroll
      for (int ct = 0; ct < NT; ++ct)
        acc[rt][ct] = (f32x4){0.f, 0.f, 0.f, 0.f};
  }

#pragma unroll
  for (int kk = 0; kk < KS1 + KS2; ++kk) {
    bf16x8 a[4];
    if (kk < KS1) {
      const int koff = kk * 32 + l4 * 8;
#pragma unroll
      for (int rt = 0; rt < 4; ++rt)
        a[rt] = *(const bf16x8*)&A1[(rt * 16 + l15) * sA1 + koff];
    } else {
      const int koff = (kk - KS1) * 32 + l4 * 8;
#pragma unroll
      for (int rt = 0; rt < 4; ++rt)
        a[rt] = *(const bf16x8*)&A2[(rt * 16 + l15) * sA2 + koff];
    }
    bf16x8 b[NT];
#pragma unroll
    for (int ct = 0; ct < NT; ++ct)
      b[ct] = *(const bf16x8*)&wb[(size_t)(ct * KSTRIDE + kk) * 512];
    // swapped operands: W-frag in the A slot, H-frag in the B slot
#pragma unroll
    for (int ct = 0; ct < NT; ++ct)
#pragma unroll
      for (int rt = 0; rt < 4; ++rt)
        acc[rt][ct] = __builtin_amdgcn_mfma_f32_16x16x32_bf16(b[ct], a[rt], acc[rt][ct], 0, 0, 0);
  }
}

// Swapped C/D mapping: per (rt,ct) a lane holds out[rt*16+l15][ct*16+l4*4+0..3]
// -> bias via one coalesced float4, output via one 8-byte LDS write.
template<int NT, bool RELU>
__device__ __forceinline__ void store_acc(
    const f32x4 (&acc)[4][NT], const float* bias,
    unsigned short* Out, int sO, int lane, int wid)
{
  const int l15 = lane & 15;
  const int l4  = lane >> 4;
  const int colbase = wid * (NT * 16);
#pragma unroll
  for (int ct = 0; ct < NT; ++ct) {
    const int col0 = colbase + ct * 16 + l4 * 4;
    const f32x4 bv = *(const f32x4*)&bias[col0];
#pragma unroll
    for (int rt = 0; rt < 4; ++rt) {
      const int row = rt * 16 + l15;
      float v0 = acc[rt][ct][0] + bv[0];
      float v1 = acc[rt][ct][1] + bv[1];
      float v2 = acc[rt][ct][2] + bv[2];
      float v3 = acc[rt][ct][3] + bv[3];
      if (RELU) {
        v0 = fmaxf(v0, 0.f); v1 = fmaxf(v1, 0.f);
        v2 = fmaxf(v2, 0.f); v3 = fmaxf(v3, 0.f);
      }
      uint2 u;
      u.x = (unsigned)f2bfu(v0) | ((unsigned)f2bfu(v1) << 16);
      u.y = (unsigned)f2bfu(v2) | ((unsigned)f2bfu(v3) << 16);
      *(uint2*)&Out[row * sO + col0] = u;   // (row*264+col0)%4==0 -> 8B aligned
    }
  }
}

__launch_bounds__(256, 3)
__global__ void nerf_main(const float* __restrict__ x, const float* __restrict__ d,
    const float* b0, const float* b1, const float* b2, const float* b3,
    const float* b4, const float* b5, const float* b6, const float* b7,
    const float* bsig, const float* b8, const float* b9, const float* b10,
    const float* b11, const float* b12, const float* brgb,
    float* __restrict__ out)
{
  __shared__ unsigned short H[64 * 264];   // 33792 B
  __shared__ unsigned short Xb[64 * 72];   // 9216 B; col 63 zeroed
  __shared__ unsigned short Db[64 * 40];   // 5120 B; cols 27..31 zeroed

  const int tid = threadIdx.x;
  const int lane = tid & 63;
  const int wid = tid >> 6;
  const int rowbase = blockIdx.x * RTILE;

  // ---- stage x and d tiles (fp32 -> bf16) ----
  {
    const int r = tid >> 2;      // 0..63
    const int sub = tid & 3;
    const float* xr = x + (size_t)(rowbase + r) * 63;
    for (int j = 0; j < 16; ++j) {
      const int c = sub + j * 4;        // 0..63
      Xb[r * 72 + c] = (c < 63) ? f2bfu(xr[c]) : (unsigned short)0;
    }
    const float* dr = d + (size_t)(rowbase + r) * 27;
    for (int j = 0; j < 8; ++j) {
      const int c = sub + j * 4;        // 0..31
      Db[r * 40 + c] = (c < 27) ? f2bfu(dr[c]) : (unsigned short)0;
    }
  }
  __syncthreads();

  f32x4 acc4[4][4];
  f32x4 acc2[4][2];

  // L0: reads Xb only -> write H directly (first writer)
  gemm_compute<2,0,2,4,true>(Xb, 72, nullptr, 0, g_w + OFF_W0, acc4, lane, wid);
  store_acc<4,true>(acc4, b0, H, 264, lane, wid);
  __syncthreads();

#define BIG_LAYER(OFFW, BIAS) \
  gemm_compute<8,0,8,4,true>(H, 264, nullptr, 0, g_w + OFFW, acc4, lane, wid); \
  __syncthreads(); \
  store_acc<4,true>(acc4, BIAS, H, 264, lane, wid); \
  __syncthreads();

  BIG_LAYER(OFF_W1, b1)
  BIG_LAYER(OFF_W2, b2)
  BIG_LAYER(OFF_W3, b3)
  BIG_LAYER(OFF_W4, b4)

  // L5: concat [h(256) | x(63)+pad] -> K=320
  gemm_compute<8,2,10,4,true>(H, 264, Xb, 72, g_w + OFF_W5, acc4, lane, wid);
  __syncthreads();
  store_acc<4,true>(acc4, b5, H, 264, lane, wid);
  __syncthreads();

  BIG_LAYER(OFF_W6, b6)
  BIG_LAYER(OFF_W7, b7)

  // ---- sigma head: softplus(h7 @ Wsig + bsig), h7 in H ----
  {
    const int r = tid >> 2;
    const int part = tid & 3;
    float s = 0.f;
    const unsigned short* wrow = g_w + OFF_WSIG + part * 64;
    const unsigned short* hrow = &H[r * 264 + part * 64];
#pragma unroll 8
    for (int k = 0; k < 64; ++k)
      s += bfu2f(hrow[k]) * bfu2f(wrow[k]);
    s += __shfl_xor(s, 1);
    s += __shfl_xor(s, 2);
    if (part == 0) {
      float logit = s + bsig[0];
      float sp = (logit > 0.f) ? (logit + log1pf(expf(-logit))) : log1pf(expf(logit));
      out[3 * NB + rowbase + r] = sp;
    }
  }

  // L8 (bottleneck, no relu)
  gemm_compute<8,0,8,4,true>(H, 264, nullptr, 0, g_w + OFF_W8, acc4, lane, wid);
  __syncthreads();                // also covers sigma-head reads of H
  store_acc<4,false>(acc4, b8, H, 264, lane, wid);
  __syncthreads();

  // L9: concat [h8(256) | d(27)+pad] -> K=288, N=128 (d from Db)
  gemm_compute<8,1,9,2,true>(H, 264, Db, 40, g_w + OFF_W9, acc2, lane, wid);
  __syncthreads();
  store_acc<2,true>(acc2, b9, H, 264, lane, wid);
  __syncthreads();

#define SMALL_LAYER(OFFW, BIAS) \
  gemm_compute<4,0,4,2,true>(H, 264, nullptr, 0, g_w + OFFW, acc2, lane, wid); \
  __syncthreads(); \
  store_acc<2,true>(acc2, BIAS, H, 264, lane, wid); \
  __syncthreads();

  SMALL_LAYER(OFF_W10, b10)
  SMALL_LAYER(OFF_W11, b11)
  SMALL_LAYER(OFF_W12, b12)

  // ---- rgb head: sigmoid(h12 @ Wrgb + brgb), h12 in H cols 0..127 ----
  if (tid < 192) {
    const int r = tid / 3;
    const int ch = tid - r * 3;
    float s = 0.f;
    const unsigned short* wrow = g_w + OFF_WRGB + ch * 128;
#pragma unroll 8
    for (int k = 0; k < 128; ++k)
      s += bfu2f(H[r * 264 + k]) * bfu2f(wrow[k]);
    float logit = s + brgb[ch];
    float val = 1.f / (1.f + expf(-logit));
    out[(size_t)(rowbase + r) * 3 + ch] = val;
  }
}

extern "C" void kernel_launch(void* const* d_in, const int* in_sizes, int n_in,
                              void* d_out, int out_size, void* d_ws, size_t ws_size,
                              hipStream_t stream) {
  const float* x    = (const float*)d_in[0];
  const float* dd   = (const float*)d_in[1];
  const float* W0   = (const float*)d_in[2];
  const float* b0   = (const float*)d_in[3];
  const float* W1   = (const float*)d_in[4];
  const float* b1   = (const float*)d_in[5];
  const float* W2   = (const float*)d_in[6];
  const float* b2   = (const float*)d_in[7];
  const float* W3   = (const float*)d_in[8];
  const float* b3   = (const float*)d_in[9];
  const float* W4   = (const float*)d_in[10];
  const float* b4   = (const float*)d_in[11];
  const float* W5   = (const float*)d_in[12];
  const float* b5   = (const float*)d_in[13];
  const float* W6   = (const float*)d_in[14];
  const float* b6   = (const float*)d_in[15];
  const float* W7   = (const float*)d_in[16];
  const float* b7   = (const float*)d_in[17];
  const float* Wsig = (const float*)d_in[18];
  const float* bsig = (const float*)d_in[19];
  const float* W8   = (const float*)d_in[20];
  const float* b8   = (const float*)d_in[21];
  const float* W9   = (const float*)d_in[22];
  const float* b9   = (const float*)d_in[23];
  const float* W10  = (const float*)d_in[24];
  const float* b10  = (const float*)d_in[25];
  const float* W11  = (const float*)d_in[26];
  const float* b11  = (const float*)d_in[27];
  const float* W12  = (const float*)d_in[28];
  const float* b12  = (const float*)d_in[29];
  const float* Wrgb = (const float*)d_in[30];
  const float* brgb = (const float*)d_in[31];

  prep_kernel<<<(WTOTAL + 255) / 256, 256, 0, stream>>>(
      W0, W1, W2, W3, W4, W5, W6, W7, Wsig, W8, W9, W10, W11, W12, Wrgb);

  nerf_main<<<NB / RTILE, 256, 0, stream>>>(
      x, dd, b0, b1, b2, b3, b4, b5, b6, b7, bsig, b8, b9, b10, b11, b12, brgb,
      (float*)d_out);
}

// Round 10
// 318.301 us; speedup vs baseline: 2.9546x; 1.0412x over previous
//
#include <hip/hip_runtime.h>
#include <hip/hip_bf16.h>

#define NB 262144
#define RTILE 64

typedef __bf16 bf16x8 __attribute__((ext_vector_type(8)));
typedef float f32x4 __attribute__((ext_vector_type(4)));

// ---- packed bf16 weight buffer ----
// MFMA layers fragment-ordered: fragment (colTile,ks) at
//   off + ((colTile*KSTRIDE + ks)*64 + lane)*8
// lane's elems: W[col=colTile*16+(lane&15)][k=ks*32+(lane>>4)*8+e].
// Wsig/Wrgb plain row-major.
#define OFF_W0   0        // [256][64]   (K 63->64)
#define OFF_W1   16384    // [256][256]
#define OFF_W2   81920
#define OFF_W3   147456
#define OFF_W4   212992
#define OFF_W5   278528   // [256][320]  (K 319->320; ks 8,9 = x)
#define OFF_W6   360448
#define OFF_W7   425984
#define OFF_WSIG 491520   // [1][256] plain
#define OFF_W8   491776   // [256][256]
#define OFF_W9   557312   // [128][288]  (K 283->288; ks 8 = d)
#define OFF_W10  594176   // [128][128]
#define OFF_W11  610560
#define OFF_W12  626944
#define OFF_WRGB 643328   // [3][128] plain
#define WTOTAL   643712

__device__ __align__(16) unsigned short g_w[WTOTAL];

__device__ __forceinline__ unsigned short f2bfu(float f) {
  __bf16 h = (__bf16)f;
  return __builtin_bit_cast(unsigned short, h);
}
__device__ __forceinline__ float bfu2f(unsigned short u) {
  return (float)__builtin_bit_cast(__bf16, u);
}

__global__ void prep_kernel(const float* W0, const float* W1, const float* W2,
                            const float* W3, const float* W4, const float* W5,
                            const float* W6, const float* W7, const float* Wsig,
                            const float* W8, const float* W9, const float* W10,
                            const float* W11, const float* W12, const float* Wrgb) {
  const float* srcs[15] = {W0,W1,W2,W3,W4,W5,W6,W7,Wsig,W8,W9,W10,W11,W12,Wrgb};
  const int dsto[16] = {OFF_W0,OFF_W1,OFF_W2,OFF_W3,OFF_W4,OFF_W5,OFF_W6,OFF_W7,
                        OFF_WSIG,OFF_W8,OFF_W9,OFF_W10,OFF_W11,OFF_W12,OFF_WRGB,WTOTAL};
  const int kpad[15] = {64,256,256,256,256,320,256,256,256,256,288,128,128,128,128};
  const int ksrc[15] = {63,256,256,256,256,319,256,256,256,256,283,128,128,128,128};
  int idx = blockIdx.x * blockDim.x + threadIdx.x;
  if (idx >= WTOTAL) return;
  int r = 0;
  for (int i = 1; i < 15; ++i) if (idx >= dsto[i]) r = i;
  int local = idx - dsto[r];
  float v;
  if (r == 8 || r == 14) {             // head weights: plain row-major
    int o = local / kpad[r];
    int k = local - o * kpad[r];
    v = (k < ksrc[r]) ? srcs[r][o * ksrc[r] + k] : 0.0f;
  } else {                             // MFMA layers: fragment-ordered
    const int KS = kpad[r] >> 5;
    int frag = local >> 9;
    int within = local & 511;
    int lane = within >> 3;
    int e = within & 7;
    int colTile = frag / KS;
    int ks = frag - colTile * KS;
    int col = colTile * 16 + (lane & 15);
    int k = ks * 32 + (lane >> 4) * 8 + e;
    v = (k < ksrc[r]) ? srcs[r][col * ksrc[r] + k] : 0.0f;
  }
  g_w[idx] = f2bfu(v);
}

// ---- fused MLP ----
// Round-9 structure: 4 waves, 64 rows, single H [64][264], swapped-operand
// MFMA (acc = mfma(W_frag, H_frag)) so a lane holds row rt*16+l15,
// cols ct*16+l4*4+0..3 -> b64 stores, float4 bias.
// Round 10: heads fused into register epilogues (sigma from acc4 after L7,
// rgb from acc2 after L12 -- h12 never written to LDS). Partial dots are
// shfl-reduced over the 4-lane col group, parked in small LDS buffers
// (Sb 1KB, Rb 3KB), finished by 64/192 threads after a barrier.
template<int KS1, int KS2, int KSTRIDE, int NT, bool INIT>
__device__ __forceinline__ void gemm_compute(
    const unsigned short* A1, int sA1,
    const unsigned short* A2, int sA2,
    const unsigned short* Wp,
    f32x4 (&acc)[4][NT],
    int lane, int wid)
{
  const int l15 = lane & 15;
  const int l4  = lane >> 4;
  const unsigned short* wb = Wp + (size_t)(wid * NT) * KSTRIDE * 512 + lane * 8;

  if (INIT) {
#pragma unroll
    for (int rt = 0; rt < 4; ++rt)
#pragma unroll
      for (int ct = 0; ct < NT; ++ct)
        acc[rt][ct] = (f32x4){0.f, 0.f, 0.f, 0.f};
  }

#pragma unroll
  for (int kk = 0; kk < KS1 + KS2; ++kk) {
    bf16x8 a[4];
    if (kk < KS1) {
      const int koff = kk * 32 + l4 * 8;
#pragma unroll
      for (int rt = 0; rt < 4; ++rt)
        a[rt] = *(const bf16x8*)&A1[(rt * 16 + l15) * sA1 + koff];
    } else {
      const int koff = (kk - KS1) * 32 + l4 * 8;
#pragma unroll
      for (int rt = 0; rt < 4; ++rt)
        a[rt] = *(const bf16x8*)&A2[(rt * 16 + l15) * sA2 + koff];
    }
    bf16x8 b[NT];
#pragma unroll
    for (int ct = 0; ct < NT; ++ct)
      b[ct] = *(const bf16x8*)&wb[(size_t)(ct * KSTRIDE + kk) * 512];
    // swapped operands: W-frag in the A slot, H-frag in the B slot
#pragma unroll
    for (int ct = 0; ct < NT; ++ct)
#pragma unroll
      for (int rt = 0; rt < 4; ++rt)
        acc[rt][ct] = __builtin_amdgcn_mfma_f32_16x16x32_bf16(b[ct], a[rt], acc[rt][ct], 0, 0, 0);
  }
}

template<int NT, bool RELU>
__device__ __forceinline__ void store_acc(
    const f32x4 (&acc)[4][NT], const float* bias,
    unsigned short* Out, int sO, int lane, int wid)
{
  const int l15 = lane & 15;
  const int l4  = lane >> 4;
  const int colbase = wid * (NT * 16);
#pragma unroll
  for (int ct = 0; ct < NT; ++ct) {
    const int col0 = colbase + ct * 16 + l4 * 4;
    const f32x4 bv = *(const f32x4*)&bias[col0];
#pragma unroll
    for (int rt = 0; rt < 4; ++rt) {
      const int row = rt * 16 + l15;
      float v0 = acc[rt][ct][0] + bv[0];
      float v1 = acc[rt][ct][1] + bv[1];
      float v2 = acc[rt][ct][2] + bv[2];
      float v3 = acc[rt][ct][3] + bv[3];
      if (RELU) {
        v0 = fmaxf(v0, 0.f); v1 = fmaxf(v1, 0.f);
        v2 = fmaxf(v2, 0.f); v3 = fmaxf(v3, 0.f);
      }
      uint2 u;
      u.x = (unsigned)f2bfu(v0) | ((unsigned)f2bfu(v1) << 16);
      u.y = (unsigned)f2bfu(v2) | ((unsigned)f2bfu(v3) << 16);
      *(uint2*)&Out[row * sO + col0] = u;
    }
  }
}

// L7 store + sigma partial dot (h7 . Wsig) fused. Partials per (wave,rt,l15)
// parked in Sb[wave*64 + rt*16 + l15] after shfl-reduce over the l4 group.
__device__ __forceinline__ void store_acc_sigma(
    const f32x4 (&acc)[4][4], const float* bias,
    unsigned short* Out, int sO, float* Sb, int lane, int wid)
{
  const int l15 = lane & 15;
  const int l4  = lane >> 4;
  const int colbase = wid * 64;
  float ps[4] = {0.f, 0.f, 0.f, 0.f};
#pragma unroll
  for (int ct = 0; ct < 4; ++ct) {
    const int col0 = colbase + ct * 16 + l4 * 4;
    const f32x4 bv = *(const f32x4*)&bias[col0];
    const ushort4 wu = *(const ushort4*)&g_w[OFF_WSIG + col0];
    const float w0 = bfu2f(wu.x), w1 = bfu2f(wu.y), w2 = bfu2f(wu.z), w3 = bfu2f(wu.w);
#pragma unroll
    for (int rt = 0; rt < 4; ++rt) {
      const int row = rt * 16 + l15;
      float v0 = fmaxf(acc[rt][ct][0] + bv[0], 0.f);
      float v1 = fmaxf(acc[rt][ct][1] + bv[1], 0.f);
      float v2 = fmaxf(acc[rt][ct][2] + bv[2], 0.f);
      float v3 = fmaxf(acc[rt][ct][3] + bv[3], 0.f);
      uint2 u;
      u.x = (unsigned)f2bfu(v0) | ((unsigned)f2bfu(v1) << 16);
      u.y = (unsigned)f2bfu(v2) | ((unsigned)f2bfu(v3) << 16);
      *(uint2*)&Out[row * sO + col0] = u;
      // partial uses the bf16-rounded value (matches what H readers see)
      ps[rt] += bfu2f(f2bfu(v0)) * w0 + bfu2f(f2bfu(v1)) * w1
              + bfu2f(f2bfu(v2)) * w2 + bfu2f(f2bfu(v3)) * w3;
    }
  }
#pragma unroll
  for (int rt = 0; rt < 4; ++rt) {
    ps[rt] += __shfl_xor(ps[rt], 16);
    ps[rt] += __shfl_xor(ps[rt], 32);
  }
  if (l4 == 0) {
#pragma unroll
    for (int rt = 0; rt < 4; ++rt)
      Sb[wid * 64 + rt * 16 + l15] = ps[rt];
  }
}

// L12 epilogue: rgb partial dots (relu(h12) . Wrgb[ch]) straight from acc2.
// No H write at all. Partials in Rb[((wid*4+rt)*3+ch)*16 + l15].
__device__ __forceinline__ void rgb_partial(
    const f32x4 (&acc)[4][2], const float* bias,
    float* Rb, int lane, int wid)
{
  const int l15 = lane & 15;
  const int l4  = lane >> 4;
  const int colbase = wid * 32;
  float pr[4][3] = {};
#pragma unroll
  for (int ct = 0; ct < 2; ++ct) {
    const int col0 = colbase + ct * 16 + l4 * 4;
    const f32x4 bv = *(const f32x4*)&bias[col0];
    float wf[3][4];
#pragma unroll
    for (int ch = 0; ch < 3; ++ch) {
      const ushort4 wu = *(const ushort4*)&g_w[OFF_WRGB + ch * 128 + col0];
      wf[ch][0] = bfu2f(wu.x); wf[ch][1] = bfu2f(wu.y);
      wf[ch][2] = bfu2f(wu.z); wf[ch][3] = bfu2f(wu.w);
    }
#pragma unroll
    for (int rt = 0; rt < 4; ++rt) {
      float v0 = fmaxf(acc[rt][ct][0] + bv[0], 0.f);
      float v1 = fmaxf(acc[rt][ct][1] + bv[1], 0.f);
      float v2 = fmaxf(acc[rt][ct][2] + bv[2], 0.f);
      float v3 = fmaxf(acc[rt][ct][3] + bv[3], 0.f);
#pragma unroll
      for (int ch = 0; ch < 3; ++ch)
        pr[rt][ch] += v0 * wf[ch][0] + v1 * wf[ch][1] + v2 * wf[ch][2] + v3 * wf[ch][3];
    }
  }
#pragma unroll
  for (int rt = 0; rt < 4; ++rt)
#pragma unroll
    for (int ch = 0; ch < 3; ++ch) {
      pr[rt][ch] += __shfl_xor(pr[rt][ch], 16);
      pr[rt][ch] += __shfl_xor(pr[rt][ch], 32);
    }
  if (l4 == 0) {
#pragma unroll
    for (int rt = 0; rt < 4; ++rt)
#pragma unroll
      for (int ch = 0; ch < 3; ++ch)
        Rb[((wid * 4 + rt) * 3 + ch) * 16 + l15] = pr[rt][ch];
  }
}

__launch_bounds__(256, 3)
__global__ void nerf_main(const float* __restrict__ x, const float* __restrict__ d,
    const float* b0, const float* b1, const float* b2, const float* b3,
    const float* b4, const float* b5, const float* b6, const float* b7,
    const float* bsig, const float* b8, const float* b9, const float* b10,
    const float* b11, const float* b12, const float* brgb,
    float* __restrict__ out)
{
  __shared__ unsigned short H[64 * 264];   // 33792 B
  __shared__ unsigned short Xb[64 * 72];   // 9216 B; col 63 zeroed
  __shared__ unsigned short Db[64 * 40];   // 5120 B; cols 27..31 zeroed
  __shared__ float Sb[256];                // 1024 B sigma partials
  __shared__ float Rb[768];                // 3072 B rgb partials
  // total 52224 B -> 3 blocks/CU (<= 54613)

  const int tid = threadIdx.x;
  const int lane = tid & 63;
  const int wid = tid >> 6;
  const int rowbase = blockIdx.x * RTILE;

  // ---- stage x and d tiles (fp32 -> bf16) ----
  {
    const int r = tid >> 2;      // 0..63
    const int sub = tid & 3;
    const float* xr = x + (size_t)(rowbase + r) * 63;
    for (int j = 0; j < 16; ++j) {
      const int c = sub + j * 4;        // 0..63
      Xb[r * 72 + c] = (c < 63) ? f2bfu(xr[c]) : (unsigned short)0;
    }
    const float* dr = d + (size_t)(rowbase + r) * 27;
    for (int j = 0; j < 8; ++j) {
      const int c = sub + j * 4;        // 0..31
      Db[r * 40 + c] = (c < 27) ? f2bfu(dr[c]) : (unsigned short)0;
    }
  }
  __syncthreads();

  f32x4 acc4[4][4];
  f32x4 acc2[4][2];

  // L0: reads Xb only -> write H directly (first writer)
  gemm_compute<2,0,2,4,true>(Xb, 72, nullptr, 0, g_w + OFF_W0, acc4, lane, wid);
  store_acc<4,true>(acc4, b0, H, 264, lane, wid);
  __syncthreads();

#define BIG_LAYER(OFFW, BIAS) \
  gemm_compute<8,0,8,4,true>(H, 264, nullptr, 0, g_w + OFFW, acc4, lane, wid); \
  __syncthreads(); \
  store_acc<4,true>(acc4, BIAS, H, 264, lane, wid); \
  __syncthreads();

  BIG_LAYER(OFF_W1, b1)
  BIG_LAYER(OFF_W2, b2)
  BIG_LAYER(OFF_W3, b3)
  BIG_LAYER(OFF_W4, b4)

  // L5: concat [h(256) | x(63)+pad] -> K=320
  gemm_compute<8,2,10,4,true>(H, 264, Xb, 72, g_w + OFF_W5, acc4, lane, wid);
  __syncthreads();
  store_acc<4,true>(acc4, b5, H, 264, lane, wid);
  __syncthreads();

  BIG_LAYER(OFF_W6, b6)

  // L7 + fused sigma partials
  gemm_compute<8,0,8,4,true>(H, 264, nullptr, 0, g_w + OFF_W7, acc4, lane, wid);
  __syncthreads();
  store_acc_sigma(acc4, b7, H, 264, Sb, lane, wid);
  __syncthreads();

  // finish sigma: 64 threads, Sb stable from here on
  if (tid < 64) {
    float s = Sb[tid] + Sb[64 + tid] + Sb[128 + tid] + Sb[192 + tid] + bsig[0];
    float sp = (s > 0.f) ? (s + log1pf(expf(-s))) : log1pf(expf(s));
    out[3 * NB + rowbase + tid] = sp;
  }

  // L8 (bottleneck, no relu)
  gemm_compute<8,0,8,4,true>(H, 264, nullptr, 0, g_w + OFF_W8, acc4, lane, wid);
  __syncthreads();
  store_acc<4,false>(acc4, b8, H, 264, lane, wid);
  __syncthreads();

  // L9: concat [h8(256) | d(27)+pad] -> K=288, N=128 (d from Db)
  gemm_compute<8,1,9,2,true>(H, 264, Db, 40, g_w + OFF_W9, acc2, lane, wid);
  __syncthreads();
  store_acc<2,true>(acc2, b9, H, 264, lane, wid);
  __syncthreads();

#define SMALL_LAYER(OFFW, BIAS) \
  gemm_compute<4,0,4,2,true>(H, 264, nullptr, 0, g_w + OFFW, acc2, lane, wid); \
  __syncthreads(); \
  store_acc<2,true>(acc2, BIAS, H, 264, lane, wid); \
  __syncthreads();

  SMALL_LAYER(OFF_W10, b10)
  SMALL_LAYER(OFF_W11, b11)

  // L12 + fused rgb head: h12 never touches LDS
  gemm_compute<4,0,4,2,true>(H, 264, nullptr, 0, g_w + OFF_W12, acc2, lane, wid);
  rgb_partial(acc2, b12, Rb, lane, wid);
  __syncthreads();

  if (tid < 192) {
    const int r = tid / 3;
    const int ch = tid - r * 3;
    const int rt = r >> 4;
    const int l15r = r & 15;
    float s = brgb[ch];
#pragma unroll
    for (int w = 0; w < 4; ++w)
      s += Rb[((w * 4 + rt) * 3 + ch) * 16 + l15r];
    float val = 1.f / (1.f + expf(-s));
    out[(size_t)(rowbase + r) * 3 + ch] = val;
  }
}

extern "C" void kernel_launch(void* const* d_in, const int* in_sizes, int n_in,
                              void* d_out, int out_size, void* d_ws, size_t ws_size,
                              hipStream_t stream) {
  const float* x    = (const float*)d_in[0];
  const float* dd   = (const float*)d_in[1];
  const float* W0   = (const float*)d_in[2];
  const float* b0   = (const float*)d_in[3];
  const float* W1   = (const float*)d_in[4];
  const float* b1   = (const float*)d_in[5];
  const float* W2   = (const float*)d_in[6];
  const float* b2   = (const float*)d_in[7];
  const float* W3   = (const float*)d_in[8];
  const float* b3   = (const float*)d_in[9];
  const float* W4   = (const float*)d_in[10];
  const float* b4   = (const float*)d_in[11];
  const float* W5   = (const float*)d_in[12];
  const float* b5   = (const float*)d_in[13];
  const float* W6   = (const float*)d_in[14];
  const float* b6   = (const float*)d_in[15];
  const float* W7   = (const float*)d_in[16];
  const float* b7   = (const float*)d_in[17];
  const float* Wsig = (const float*)d_in[18];
  const float* bsig = (const float*)d_in[19];
  const float* W8   = (const float*)d_in[20];
  const float* b8   = (const float*)d_in[21];
  const float* W9   = (const float*)d_in[22];
  const float* b9   = (const float*)d_in[23];
  const float* W10  = (const float*)d_in[24];
  const float* b10  = (const float*)d_in[25];
  const float* W11  = (const float*)d_in[26];
  const float* b11  = (const float*)d_in[27];
  const float* W12  = (const float*)d_in[28];
  const float* b12  = (const float*)d_in[29];
  const float* Wrgb = (const float*)d_in[30];
  const float* brgb = (const float*)d_in[31];

  prep_kernel<<<(WTOTAL + 255) / 256, 256, 0, stream>>>(
      W0, W1, W2, W3, W4, W5, W6, W7, Wsig, W8, W9, W10, W11, W12, Wrgb);

  nerf_main<<<NB / RTILE, 256, 0, stream>>>(
      x, dd, b0, b1, b2, b3, b4, b5, b6, b7, bsig, b8, b9, b10, b11, b12, brgb,
      (float*)d_out);
}